// Round 16
// baseline (1108.087 us; speedup 1.0000x reference)
//
#include <hip/hip_runtime.h>
#include <hip/hip_bf16.h>
#include <stdint.h>

#define T_TOK 16384
#define HDIM  1024
#define FDIM  4096
#define NE    8
#define CAP   2560   // ceil(1.25 * 16384 / 8)

typedef __attribute__((ext_vector_type(8))) __bf16 bf16x8;
typedef __attribute__((ext_vector_type(4))) float  f32x4;

#define MFMA_BF16 __builtin_amdgcn_mfma_f32_16x16x32_bf16
#define VMCNT0()  asm volatile("s_waitcnt vmcnt(0)" ::: "memory")
#define VMCNT2()  asm volatile("s_waitcnt vmcnt(2)" ::: "memory")
#define VMCNT10() asm volatile("s_waitcnt vmcnt(10)" ::: "memory")
#define LGKM0()   asm volatile("s_waitcnt lgkmcnt(0)" ::: "memory")
#define BAR()     __builtin_amdgcn_s_barrier()
#define SCHED0()  __builtin_amdgcn_sched_barrier(0)

__device__ __forceinline__ unsigned short f2bf(float f) {
  union { float f; unsigned u; } c; c.f = f;
  unsigned u = c.u;
  return (unsigned short)((u + 0x7FFFu + ((u >> 16) & 1u)) >> 16);
}

__device__ __forceinline__ float bf2f(unsigned short u) {
  union { unsigned u; float f; } c; c.u = ((unsigned)u) << 16;
  return c.f;
}

__device__ __forceinline__ void gload_lds16(const void* g, void* lds) {
  __builtin_amdgcn_global_load_lds((const __attribute__((address_space(1))) void*)g,
                                   (__attribute__((address_space(3))) void*)lds,
                                   16, 0, 0);
}

// ---------------- transpose + fp32->bf16 convert: in (E,R,Cc) f32 -> out (E,Cc,R) bf16
__global__ __launch_bounds__(256)
void transpose_cvt(const float* __restrict__ in, unsigned short* __restrict__ out,
                   int R, int Cc) {
  __shared__ unsigned short tile[64][68];
  int e  = blockIdx.z;
  int rb = blockIdx.y << 6, cb = blockIdx.x << 6;
  const float* inp = in + (size_t)e * R * Cc;
  unsigned short* op = out + (size_t)e * R * Cc;
  int lc  = threadIdx.x & 63;
  int lr0 = threadIdx.x >> 6;
#pragma unroll
  for (int rr = 0; rr < 64; rr += 4) {
    int r = rr + lr0;
    float v = inp[(size_t)(rb + r) * Cc + cb + lc];
    tile[lc][r] = f2bf(v);
  }
  __syncthreads();
  int c0 = threadIdx.x >> 3;
  int h0 = (threadIdx.x & 7) << 3;
#pragma unroll
  for (int cc = 0; cc < 64; cc += 32) {
    int c = cc + c0;
    uint2 v0 = *(const uint2*)&tile[c][h0];
    uint2 v1 = *(const uint2*)&tile[c][h0 + 4];
    uint4 v; v.x = v0.x; v.y = v0.y; v.z = v1.x; v.w = v1.y;
    *(uint4*)(op + (size_t)(cb + c) * R + rb + h0) = v;
  }
}

// ---------------- transpose gate/up into interleaved wgu: rows (grp*64 + 0..31)=gate, (+32..63)=up
__global__ __launch_bounds__(256)
void transpose_cvt_gu(const float* __restrict__ in, unsigned short* __restrict__ out, int up) {
  __shared__ unsigned short tile[64][68];
  int e  = blockIdx.z;
  int rb = blockIdx.y << 6, cb = blockIdx.x << 6;
  const float* inp = in + (size_t)e * HDIM * FDIM;
  unsigned short* op = out + (size_t)e * 2 * FDIM * HDIM;
  int lc  = threadIdx.x & 63;
  int lr0 = threadIdx.x >> 6;
#pragma unroll
  for (int rr = 0; rr < 64; rr += 4) {
    int r = rr + lr0;
    float v = inp[(size_t)(rb + r) * FDIM + cb + lc];
    tile[lc][r] = f2bf(v);
  }
  __syncthreads();
  int c0 = threadIdx.x >> 3;
  int h0 = (threadIdx.x & 7) << 3;
#pragma unroll
  for (int cc = 0; cc < 64; cc += 32) {
    int c = cc + c0;
    int C = cb + c;
    int orow = ((C >> 5) << 6) + (C & 31) + (up << 5);
    uint2 v0 = *(const uint2*)&tile[c][h0];
    uint2 v1 = *(const uint2*)&tile[c][h0 + 4];
    uint4 v; v.x = v0.x; v.y = v0.y; v.z = v1.x; v.w = v1.y;
    *(uint4*)(op + (size_t)orow * HDIM + rb + h0) = v;
  }
}

// ---------------- router: 1 wave per token, fp32 logits, top-2
__global__ __launch_bounds__(256)
void router_kernel(const float* __restrict__ tokens, const float* __restrict__ wr,
                   int* __restrict__ topsel, float* __restrict__ wts) {
  int lane = threadIdx.x & 63;
  int t = (blockIdx.x << 2) + (threadIdx.x >> 6);
  const float* tok = tokens + (size_t)t * HDIM;
  float acc[8];
#pragma unroll
  for (int i = 0; i < 8; ++i) acc[i] = 0.f;
#pragma unroll
  for (int j = 0; j < 4; ++j) {
    int h0 = j * 256 + lane * 4;
    float4 tv = *(const float4*)(tok + h0);
    const float* w = wr + (size_t)h0 * 8;
#pragma unroll
    for (int q = 0; q < 4; ++q) {
      float xv = ((const float*)&tv)[q];
      float4 wa = *(const float4*)(w + q * 8);
      float4 wb = *(const float4*)(w + q * 8 + 4);
      acc[0] += xv * wa.x; acc[1] += xv * wa.y; acc[2] += xv * wa.z; acc[3] += xv * wa.w;
      acc[4] += xv * wb.x; acc[5] += xv * wb.y; acc[6] += xv * wb.z; acc[7] += xv * wb.w;
    }
  }
#pragma unroll
  for (int off = 1; off < 64; off <<= 1) {
#pragma unroll
    for (int i = 0; i < 8; ++i) acc[i] += __shfl_xor(acc[i], off, 64);
  }
  if (lane == 0) {
    int e0 = 0; float v0 = acc[0];
#pragma unroll
    for (int i = 1; i < 8; ++i) if (acc[i] > v0) { v0 = acc[i]; e0 = i; }
    int e1 = -1; float v1 = -3.4e38f;
#pragma unroll
    for (int i = 0; i < 8; ++i) if (i != e0 && acc[i] > v1) { v1 = acc[i]; e1 = i; }
    float w0 = 1.f / (1.f + __expf(v1 - v0));
    topsel[t * 2] = e0; topsel[t * 2 + 1] = e1;
    wts[t * 2] = w0;    wts[t * 2 + 1] = 1.f - w0;
  }
}

// ---------------- dispatch: per-expert block; 3-pass (count / scan / assign)
__global__ __launch_bounds__(256)
void dispatch_kernel(const int* __restrict__ topsel, int* __restrict__ slot,
                     int* __restrict__ src_tok) {
  int e = blockIdx.x;           // 8 blocks
  int w = threadIdx.x >> 6, lane = threadIdx.x & 63;
  __shared__ int gcnt[2][256];
  __shared__ int tot[2];
#pragma unroll
  for (int k = 0; k < 2; ++k)
    for (int g = w; g < 256; g += 4) {
      int ch = topsel[(g * 64 + lane) * 2 + k];
      unsigned long long m = __ballot(ch == e);
      if (lane == 0) gcnt[k][g] = __popcll(m);
    }
  __syncthreads();
  if (w < 2) {
    int k = w;
    int c0 = gcnt[k][lane * 4], c1 = gcnt[k][lane * 4 + 1];
    int c2 = gcnt[k][lane * 4 + 2], c3 = gcnt[k][lane * 4 + 3];
    int s = c0 + c1 + c2 + c3;
    int inc = s;
#pragma unroll
    for (int off = 1; off < 64; off <<= 1) {
      int v = __shfl_up(inc, off, 64);
      if (lane >= off) inc += v;
    }
    int base = inc - s;
    gcnt[k][lane * 4] = base;
    gcnt[k][lane * 4 + 1] = base + c0;
    gcnt[k][lane * 4 + 2] = base + c0 + c1;
    gcnt[k][lane * 4 + 3] = base + c0 + c1 + c2;
    if (lane == 63) tot[k] = inc;
  }
  __syncthreads();
#pragma unroll
  for (int k = 0; k < 2; ++k) {
    int kbase = (k == 1) ? tot[0] : 0;
    for (int g = w; g < 256; g += 4) {
      int t = g * 64 + lane;
      int ch = topsel[t * 2 + k];
      unsigned long long m = __ballot(ch == e);
      if (ch == e) {
        unsigned long long lmask = lane ? (~0ull >> (64 - lane)) : 0ull;
        int r = kbase + gcnt[k][g] + __popcll(m & lmask);
        if (r < CAP) { slot[t * 2 + k] = r; src_tok[e * CAP + r] = t; }
        else         { slot[t * 2 + k] = -1; }
      }
    }
  }
}

// ---------------- gather tokens -> bf16 x (E*CAP, HDIM); zero unfilled slots
__global__ __launch_bounds__(128)
void gather_x(const float* __restrict__ tokens, const int* __restrict__ src_tok,
              unsigned short* __restrict__ x) {
  int s = blockIdx.x;
  int t = src_tok[s];
  unsigned short* xr = x + (size_t)s * HDIM + threadIdx.x * 8;
  uint4 v = {0u, 0u, 0u, 0u};
  if (t >= 0) {
    const float* tr = tokens + (size_t)t * HDIM + threadIdx.x * 8;
    float4 a = *(const float4*)tr;
    float4 b = *(const float4*)(tr + 4);
    v.x = (unsigned)f2bf(a.x) | ((unsigned)f2bf(a.y) << 16);
    v.y = (unsigned)f2bf(a.z) | ((unsigned)f2bf(a.w) << 16);
    v.z = (unsigned)f2bf(b.x) | ((unsigned)f2bf(b.y) << 16);
    v.w = (unsigned)f2bf(b.z) | ((unsigned)f2bf(b.w) << 16);
  }
  *(uint4*)xr = v;
}

// ================= 4-phase/tile 256x256 BK=64 mainloop, A DIRECT FROM GLOBAL =========
// A frags are wave-private: each lane loads its 16B A fragments straight from global
// (k-contiguous, L2-hot) -> LDS holds ONLY B (2x32KB dbuf). LDS traffic/tile drops
// 256KB->160KB (B frag reads 128KB + stage writes 32KB). A-reg loads are issued AFTER
// each set's last mmq (aB at P3-end, aA at P4-end; register-WAR safe) with SCHED0 pins.
// FIFO/tile: [B0st x2 @P1, B1st x2 @P2, aB x4 @P3, aA x4 @P4]; vmcnt(10)@P4-end
// retires B0(t+1) before its P1 ds_reads; vmcnt(2)@P1 (pre-mmq) retires B1/aB/aA(t).
// WAR on LDS: staged-over region's readers lgkm-drained >=4 barriers prior.
__device__ __forceinline__ void mainloopA(const unsigned short* __restrict__ Ag,
                                          const unsigned short* __restrict__ Bg,
                                          int lda, int ldb, int nkt,
                                          unsigned short* lds, f32x4 (&acc)[4][8]) {
  constexpr int BELB = 256 * 64 * 2;   // 32 KB per parity
  constexpr int BHB  = 128 * 128;      // 16 KB per B half
  int tid = threadIdx.x, lane = tid & 63, wid = tid >> 6;
  int qr = wid >> 1, qc = wid & 1;
  int fr = lane & 15, fg = lane >> 4;

  char* ldsc = (char*)lds;
  int swz0 = ((fg       ^ (fr & 7)) << 4);
  int swz1 = (((4 | fg) ^ (fr & 7)) << 4);
  const char* b_b0 = ldsc + (qc * 64 + fr) * 128 + swz0;
  const char* b_b1 = ldsc + (qc * 64 + fr) * 128 + swz1;

  int srow = tid >> 3;
  int sl8  = ((tid & 7) ^ (srow & 7)) * 8;   // pre-swizzled global column offset (ushorts)

  auto stB = [&](int nh, int kt, int qb) {
    char* dst = ldsc + qb + nh * BHB;
    gload_lds16(Bg + (size_t)(nh * 128 + srow) * ldb + kt + sl8, dst + tid * 16);
    gload_lds16(Bg + (size_t)(nh * 128 + 64 + srow) * ldb + kt + sl8, dst + tid * 16 + 8192);
  };

  // per-lane A bases: rows mh*128 + qr*32 + mf*16 + fr, col fg*8
  const unsigned short* a00 = Ag + (size_t)(qr * 32 + fr) * lda + fg * 8;
  const unsigned short* a01 = a00 + 16 * (size_t)lda;
  const unsigned short* a10 = a00 + 128 * (size_t)lda;
  const unsigned short* a11 = a00 + 144 * (size_t)lda;

  bf16x8 aA[2][2], aB[2][2], bA[4][2], bB[4][2];
  auto ldA = [&](bf16x8 (&d)[2][2], const unsigned short* b0, const unsigned short* b1, int kO) {
    d[0][0] = *(const bf16x8*)(b0 + kO);
    d[0][1] = *(const bf16x8*)(b0 + kO + 32);
    d[1][0] = *(const bf16x8*)(b1 + kO);
    d[1][1] = *(const bf16x8*)(b1 + kO + 32);
  };
  auto rdB = [&](bf16x8 (&d)[4][2], int nh, int qb) {
#pragma unroll
    for (int nf = 0; nf < 4; ++nf) {
      d[nf][0] = *(const bf16x8*)(b_b0 + qb + nh * BHB + nf * 2048);
      d[nf][1] = *(const bf16x8*)(b_b1 + qb + nh * BHB + nf * 2048);
    }
  };
  auto mmq = [&](bf16x8 (&A)[2][2], bf16x8 (&B)[4][2], int mh, int nh) {
    __builtin_amdgcn_s_setprio(1);
#pragma unroll
    for (int kk = 0; kk < 2; ++kk)
#pragma unroll
      for (int mf = 0; mf < 2; ++mf)
#pragma unroll
        for (int nf = 0; nf < 4; ++nf)
          acc[mh * 2 + mf][nh * 4 + nf] =
              MFMA_BF16(A[mf][kk], B[nf][kk], acc[mh * 2 + mf][nh * 4 + nf], 0, 0, 0);
    __builtin_amdgcn_s_setprio(0);
  };

  // prologue: B(0) both halves -> parity0; A(0) frag sets; full drain
  stB(0, 0, 0); stB(1, 0, 0);
  ldA(aA, a00, a01, 0); ldA(aB, a10, a11, 0);
  VMCNT0();
  BAR();

  for (int t = 0; t < nkt; ++t) {
    int q0 = (t & 1) ? BELB : 0, q1 = BELB - q0;
    int kt1 = ((t + 1 < nkt) ? t + 1 : nkt - 1) * 64;

    // P1: rd bA(B0,t); stage B0(t+1); vmcnt(2) retires B1/aB/aA(t); mmq Q(0,0)
    rdB(bA, 0, q0);
    stB(0, kt1, q1);
    SCHED0();
    LGKM0();
    VMCNT2();
    SCHED0();
    mmq(aA, bA, 0, 0);
    BAR();

    // P2: rd bB(B1,t) (drained under MFMA); stage B1(t+1); mmq Q(1,0)
    rdB(bB, 1, q0);
    stB(1, kt1, q1);
    SCHED0();
    mmq(aB, bA, 1, 0);
    LGKM0();
    BAR();

    // P3: mmq Q(1,1); then load aB(t+1) (after aB's last use)
    mmq(aB, bB, 1, 1);
    SCHED0();
    ldA(aB, a10, a11, kt1);
    SCHED0();
    BAR();

    // P4: mmq Q(0,1); then load aA(t+1); vmcnt(10) retires B0(t+1) stage
    mmq(aA, bB, 0, 1);
    SCHED0();
    ldA(aA, a00, a01, kt1);
    SCHED0();
    VMCNT10();
    BAR();
  }
}

// ---------------- GEMM1: h = silu(x@Wg) * (x@Wu), interleaved wgu B; 256x256
__global__ __launch_bounds__(512, 1)
void gemm1_kernel(const unsigned short* __restrict__ x, const unsigned short* __restrict__ wgu,
                  unsigned short* __restrict__ h) {
  __shared__ unsigned short lds[2 * 256 * 64];
  int flat = blockIdx.x;                 // 2560 blocks
  int e = flat & 7, idx = flat >> 3;     // expert per XCD
  int c = idx >> 4, i = idx & 15;        // chunks of 16 blocks (8bx x 2by)
  int cbx = c / 5, cby = c % 5;
  int bx = cbx * 8 + (i & 7), by = cby * 2 + (i >> 3);
  const unsigned short* Ag = x   + ((size_t)e * CAP + (size_t)by * 256) * HDIM;
  const unsigned short* Bg = wgu + ((size_t)e * 2 * FDIM + (size_t)bx * 256) * HDIM;
  f32x4 acc[4][8];
#pragma unroll
  for (int m = 0; m < 4; ++m)
#pragma unroll
    for (int n = 0; n < 8; ++n) acc[m][n] = (f32x4){0.f, 0.f, 0.f, 0.f};
  mainloopA(Ag, Bg, HDIM, HDIM, HDIM / 64, lds, acc);

  int lane = threadIdx.x & 63, wid = threadIdx.x >> 6;
  int qr = wid >> 1, qc = wid & 1, fr = lane & 15, fg = lane >> 4;
  size_t rbase = (size_t)e * CAP + by * 256;
#pragma unroll
  for (int mi = 0; mi < 4; ++mi) {
    int row0 = (mi >> 1) * 128 + qr * 32 + (mi & 1) * 16 + fg * 4;
#pragma unroll
    for (int nh = 0; nh < 2; ++nh)
#pragma unroll
      for (int nf = 0; nf < 2; ++nf) {
        int fcol = bx * 128 + (nh * 2 + qc) * 32 + nf * 16 + fr;
#pragma unroll
        for (int v = 0; v < 4; ++v) {
          float g = acc[mi][nh * 4 + nf][v];
          float u = acc[mi][nh * 4 + nf + 2][v];
          float s = g / (1.f + __expf(-g));
          h[(rbase + row0 + v) * FDIM + fcol] = f2bf(s * u);
        }
      }
  }
}

// ---------------- GEMM2: y_ks = h[:,ks*2048:+2048] @ Wd[ks-half]; 256x256, bf16 out
__global__ __launch_bounds__(512, 1)
void gemm2_kernel(const unsigned short* __restrict__ h, const unsigned short* __restrict__ wdT,
                  unsigned short* __restrict__ y0, unsigned short* __restrict__ y1) {
  __shared__ unsigned short lds[2 * 256 * 64];
  int flat = blockIdx.x;                 // 640 blocks
  int e = flat & 7, idx = flat >> 3;     // [0,80)
  int ks = idx & 1, r2 = idx >> 1;       // [0,40)
  int bx = r2 & 3, by = r2 >> 2;         // 4 bx x 10 by
  int k0 = ks * 2048;
  const unsigned short* Ag = h   + ((size_t)e * CAP  + (size_t)by * 256) * FDIM + k0;
  const unsigned short* Bg = wdT + ((size_t)e * HDIM + (size_t)bx * 256) * FDIM + k0;
  f32x4 acc[4][8];
#pragma unroll
  for (int m = 0; m < 4; ++m)
#pragma unroll
    for (int n = 0; n < 8; ++n) acc[m][n] = (f32x4){0.f, 0.f, 0.f, 0.f};
  mainloopA(Ag, Bg, FDIM, FDIM, 2048 / 64, lds, acc);

  unsigned short* yk = ks ? y1 : y0;
  int lane = threadIdx.x & 63, wid = threadIdx.x >> 6;
  int qr = wid >> 1, qc = wid & 1, fr = lane & 15, fg = lane >> 4;
  size_t rbase = (size_t)e * CAP + by * 256;
#pragma unroll
  for (int mi = 0; mi < 4; ++mi) {
    int row0 = (mi >> 1) * 128 + qr * 32 + (mi & 1) * 16 + fg * 4;
#pragma unroll
    for (int nh = 0; nh < 2; ++nh)
#pragma unroll
      for (int nf = 0; nf < 4; ++nf) {
        int col = bx * 256 + nh * 128 + qc * 64 + nf * 16 + fr;
#pragma unroll
        for (int v = 0; v < 4; ++v)
          yk[(rbase + row0 + v) * HDIM + col] = f2bf(acc[mi][nh * 4 + nf][v]);
      }
  }
}

// ---------------- combine: out[t] = sum_k w_k * (y0[e_k,slot_k] + y1[e_k,slot_k])
__global__ __launch_bounds__(256)
void combine_kernel(const unsigned short* __restrict__ y0, const unsigned short* __restrict__ y1,
                    const int* __restrict__ topsel, const int* __restrict__ slot,
                    const float* __restrict__ wts, float* __restrict__ out) {
  int t = blockIdx.x;
  int i = threadIdx.x * 4;
  float4 s = {0.f, 0.f, 0.f, 0.f};
#pragma unroll
  for (int k = 0; k < 2; ++k) {
    int sl = slot[t * 2 + k];
    if (sl >= 0) {
      int e = topsel[t * 2 + k];
      float w = wts[t * 2 + k];
      size_t base = ((size_t)e * CAP + sl) * HDIM + i;
      uint2 a = *(const uint2*)(y0 + base);
      uint2 b = *(const uint2*)(y1 + base);
      s.x += w * (bf2f((unsigned short)(a.x & 0xFFFF)) + bf2f((unsigned short)(b.x & 0xFFFF)));
      s.y += w * (bf2f((unsigned short)(a.x >> 16))    + bf2f((unsigned short)(b.x >> 16)));
      s.z += w * (bf2f((unsigned short)(a.y & 0xFFFF)) + bf2f((unsigned short)(b.y & 0xFFFF)));
      s.w += w * (bf2f((unsigned short)(a.y >> 16))    + bf2f((unsigned short)(b.y >> 16)));
    }
  }
  *(float4*)(out + (size_t)t * HDIM + i) = s;
}

extern "C" void kernel_launch(void* const* d_in, const int* in_sizes, int n_in,
                              void* d_out, int out_size, void* d_ws, size_t ws_size,
                              hipStream_t stream) {
  const float* tokens   = (const float*)d_in[0];
  const float* w_router = (const float*)d_in[1];
  const float* w_gate   = (const float*)d_in[2];
  const float* w_up     = (const float*)d_in[3];
  const float* w_down   = (const float*)d_in[4];
  float* out = (float*)d_out;
  char* ws = (char*)d_ws;

  const size_t WGU = (size_t)NE * 2 * FDIM * HDIM * 2;  // 128 MiB interleaved gate/up bf16
  const size_t WD  = (size_t)NE * HDIM * FDIM * 2;      // 64 MiB
  const size_t XB  = (size_t)NE * CAP * HDIM * 2;       // 40 MiB
  const size_t HB  = (size_t)NE * CAP * FDIM * 2;       // 160 MiB
  const size_t YB  = (size_t)NE * CAP * HDIM * 2;       // 40 MiB (bf16 y per split)
  unsigned short* wguT = (unsigned short*)(ws);
  unsigned short* wdT  = (unsigned short*)(ws + WGU);
  unsigned short* xbuf = (unsigned short*)(ws + WGU + WD);
  unsigned short* hbuf = (unsigned short*)(ws + WGU + WD + XB);
  unsigned short* ybuf0 = (unsigned short*)(ws);        // aliases wguT (dead after gemm1)
  unsigned short* ybuf1 = (unsigned short*)(ws + YB);   // still within WGU's 128 MiB
  char* tail = ws + WGU + WD + XB + HB;
  int*   topsel  = (int*)tail;
  float* wtsv    = (float*)(tail + (size_t)T_TOK * 2 * 4);
  int*   slotv   = (int*)(tail + (size_t)T_TOK * 2 * 8);
  int*   src_tok = (int*)(tail + (size_t)T_TOK * 2 * 12);

  hipMemsetAsync(src_tok, 0xFF, (size_t)NE * CAP * 4, stream);

  transpose_cvt_gu<<<dim3(FDIM / 64, HDIM / 64, NE), 256, 0, stream>>>(w_gate, wguT, 0);
  transpose_cvt_gu<<<dim3(FDIM / 64, HDIM / 64, NE), 256, 0, stream>>>(w_up,   wguT, 1);
  transpose_cvt<<<dim3(HDIM / 64, FDIM / 64, NE), 256, 0, stream>>>(w_down, wdT, FDIM, HDIM);

  router_kernel<<<T_TOK / 4, 256, 0, stream>>>(tokens, w_router, topsel, wtsv);
  dispatch_kernel<<<NE, 256, 0, stream>>>(topsel, slotv, src_tok);
  gather_x<<<NE * CAP, 128, 0, stream>>>(tokens, src_tok, xbuf);

  gemm1_kernel<<<2560, 512, 0, stream>>>(xbuf, wguT, hbuf);
  gemm2_kernel<<<640, 512, 0, stream>>>(hbuf, wdT, ybuf0, ybuf1);

  combine_kernel<<<T_TOK, 256, 0, stream>>>(ybuf0, ybuf1, topsel, slotv, wtsv, out);
}

// Round 17
// 746.455 us; speedup vs baseline: 1.4845x; 1.4845x over previous
//
#include <hip/hip_runtime.h>
#include <hip/hip_bf16.h>
#include <stdint.h>

#define T_TOK 16384
#define HDIM  1024
#define FDIM  4096
#define NE    8
#define CAP   2560   // ceil(1.25 * 16384 / 8)

typedef __attribute__((ext_vector_type(8))) __bf16 bf16x8;
typedef __attribute__((ext_vector_type(4))) float  f32x4;

#define MFMA_BF16 __builtin_amdgcn_mfma_f32_16x16x32_bf16
#define VMCNT3()  asm volatile("s_waitcnt vmcnt(3)" ::: "memory")
#define VMCNT4()  asm volatile("s_waitcnt vmcnt(4)" ::: "memory")
#define LGKM0()   asm volatile("s_waitcnt lgkmcnt(0)" ::: "memory")
#define BAR()     __builtin_amdgcn_s_barrier()
#define SCHED0()  __builtin_amdgcn_sched_barrier(0)

__device__ __forceinline__ unsigned short f2bf(float f) {
  union { float f; unsigned u; } c; c.f = f;
  unsigned u = c.u;
  return (unsigned short)((u + 0x7FFFu + ((u >> 16) & 1u)) >> 16);
}

__device__ __forceinline__ float bf2f(unsigned short u) {
  union { unsigned u; float f; } c; c.u = ((unsigned)u) << 16;
  return c.f;
}

__device__ __forceinline__ void gload_lds16(const void* g, void* lds) {
  __builtin_amdgcn_global_load_lds((const __attribute__((address_space(1))) void*)g,
                                   (__attribute__((address_space(3))) void*)lds,
                                   16, 0, 0);
}

// ---------------- transpose + fp32->bf16 convert: in (E,R,Cc) f32 -> out (E,Cc,R) bf16
__global__ __launch_bounds__(256)
void transpose_cvt(const float* __restrict__ in, unsigned short* __restrict__ out,
                   int R, int Cc) {
  __shared__ unsigned short tile[64][68];
  int e  = blockIdx.z;
  int rb = blockIdx.y << 6, cb = blockIdx.x << 6;
  const float* inp = in + (size_t)e * R * Cc;
  unsigned short* op = out + (size_t)e * R * Cc;
  int lc  = threadIdx.x & 63;
  int lr0 = threadIdx.x >> 6;
#pragma unroll
  for (int rr = 0; rr < 64; rr += 4) {
    int r = rr + lr0;
    float v = inp[(size_t)(rb + r) * Cc + cb + lc];
    tile[lc][r] = f2bf(v);
  }
  __syncthreads();
  int c0 = threadIdx.x >> 3;
  int h0 = (threadIdx.x & 7) << 3;
#pragma unroll
  for (int cc = 0; cc < 64; cc += 32) {
    int c = cc + c0;
    uint2 v0 = *(const uint2*)&tile[c][h0];
    uint2 v1 = *(const uint2*)&tile[c][h0 + 4];
    uint4 v; v.x = v0.x; v.y = v0.y; v.z = v1.x; v.w = v1.y;
    *(uint4*)(op + (size_t)(cb + c) * R + rb + h0) = v;
  }
}

// ---------------- transpose gate/up into interleaved wgu: rows (grp*64 + 0..31)=gate, (+32..63)=up
__global__ __launch_bounds__(256)
void transpose_cvt_gu(const float* __restrict__ in, unsigned short* __restrict__ out, int up) {
  __shared__ unsigned short tile[64][68];
  int e  = blockIdx.z;
  int rb = blockIdx.y << 6, cb = blockIdx.x << 6;
  const float* inp = in + (size_t)e * HDIM * FDIM;
  unsigned short* op = out + (size_t)e * 2 * FDIM * HDIM;
  int lc  = threadIdx.x & 63;
  int lr0 = threadIdx.x >> 6;
#pragma unroll
  for (int rr = 0; rr < 64; rr += 4) {
    int r = rr + lr0;
    float v = inp[(size_t)(rb + r) * FDIM + cb + lc];
    tile[lc][r] = f2bf(v);
  }
  __syncthreads();
  int c0 = threadIdx.x >> 3;
  int h0 = (threadIdx.x & 7) << 3;
#pragma unroll
  for (int cc = 0; cc < 64; cc += 32) {
    int c = cc + c0;
    int C = cb + c;
    int orow = ((C >> 5) << 6) + (C & 31) + (up << 5);
    uint2 v0 = *(const uint2*)&tile[c][h0];
    uint2 v1 = *(const uint2*)&tile[c][h0 + 4];
    uint4 v; v.x = v0.x; v.y = v0.y; v.z = v1.x; v.w = v1.y;
    *(uint4*)(op + (size_t)orow * HDIM + rb + h0) = v;
  }
}

// ---------------- router: 1 wave per token, fp32 logits, top-2
__global__ __launch_bounds__(256)
void router_kernel(const float* __restrict__ tokens, const float* __restrict__ wr,
                   int* __restrict__ topsel, float* __restrict__ wts) {
  int lane = threadIdx.x & 63;
  int t = (blockIdx.x << 2) + (threadIdx.x >> 6);
  const float* tok = tokens + (size_t)t * HDIM;
  float acc[8];
#pragma unroll
  for (int i = 0; i < 8; ++i) acc[i] = 0.f;
#pragma unroll
  for (int j = 0; j < 4; ++j) {
    int h0 = j * 256 + lane * 4;
    float4 tv = *(const float4*)(tok + h0);
    const float* w = wr + (size_t)h0 * 8;
#pragma unroll
    for (int q = 0; q < 4; ++q) {
      float xv = ((const float*)&tv)[q];
      float4 wa = *(const float4*)(w + q * 8);
      float4 wb = *(const float4*)(w + q * 8 + 4);
      acc[0] += xv * wa.x; acc[1] += xv * wa.y; acc[2] += xv * wa.z; acc[3] += xv * wa.w;
      acc[4] += xv * wb.x; acc[5] += xv * wb.y; acc[6] += xv * wb.z; acc[7] += xv * wb.w;
    }
  }
#pragma unroll
  for (int off = 1; off < 64; off <<= 1) {
#pragma unroll
    for (int i = 0; i < 8; ++i) acc[i] += __shfl_xor(acc[i], off, 64);
  }
  if (lane == 0) {
    int e0 = 0; float v0 = acc[0];
#pragma unroll
    for (int i = 1; i < 8; ++i) if (acc[i] > v0) { v0 = acc[i]; e0 = i; }
    int e1 = -1; float v1 = -3.4e38f;
#pragma unroll
    for (int i = 0; i < 8; ++i) if (i != e0 && acc[i] > v1) { v1 = acc[i]; e1 = i; }
    float w0 = 1.f / (1.f + __expf(v1 - v0));
    topsel[t * 2] = e0; topsel[t * 2 + 1] = e1;
    wts[t * 2] = w0;    wts[t * 2 + 1] = 1.f - w0;
  }
}

// ---------------- dispatch: per-expert block; 3-pass (count / scan / assign)
__global__ __launch_bounds__(256)
void dispatch_kernel(const int* __restrict__ topsel, int* __restrict__ slot,
                     int* __restrict__ src_tok) {
  int e = blockIdx.x;           // 8 blocks
  int w = threadIdx.x >> 6, lane = threadIdx.x & 63;
  __shared__ int gcnt[2][256];
  __shared__ int tot[2];
#pragma unroll
  for (int k = 0; k < 2; ++k)
    for (int g = w; g < 256; g += 4) {
      int ch = topsel[(g * 64 + lane) * 2 + k];
      unsigned long long m = __ballot(ch == e);
      if (lane == 0) gcnt[k][g] = __popcll(m);
    }
  __syncthreads();
  if (w < 2) {
    int k = w;
    int c0 = gcnt[k][lane * 4], c1 = gcnt[k][lane * 4 + 1];
    int c2 = gcnt[k][lane * 4 + 2], c3 = gcnt[k][lane * 4 + 3];
    int s = c0 + c1 + c2 + c3;
    int inc = s;
#pragma unroll
    for (int off = 1; off < 64; off <<= 1) {
      int v = __shfl_up(inc, off, 64);
      if (lane >= off) inc += v;
    }
    int base = inc - s;
    gcnt[k][lane * 4] = base;
    gcnt[k][lane * 4 + 1] = base + c0;
    gcnt[k][lane * 4 + 2] = base + c0 + c1;
    gcnt[k][lane * 4 + 3] = base + c0 + c1 + c2;
    if (lane == 63) tot[k] = inc;
  }
  __syncthreads();
#pragma unroll
  for (int k = 0; k < 2; ++k) {
    int kbase = (k == 1) ? tot[0] : 0;
    for (int g = w; g < 256; g += 4) {
      int t = g * 64 + lane;
      int ch = topsel[t * 2 + k];
      unsigned long long m = __ballot(ch == e);
      if (ch == e) {
        unsigned long long lmask = lane ? (~0ull >> (64 - lane)) : 0ull;
        int r = kbase + gcnt[k][g] + __popcll(m & lmask);
        if (r < CAP) { slot[t * 2 + k] = r; src_tok[e * CAP + r] = t; }
        else         { slot[t * 2 + k] = -1; }
      }
    }
  }
}

// ---------------- gather tokens -> bf16 x (E*CAP, HDIM); zero unfilled slots
__global__ __launch_bounds__(128)
void gather_x(const float* __restrict__ tokens, const int* __restrict__ src_tok,
              unsigned short* __restrict__ x) {
  int s = blockIdx.x;
  int t = src_tok[s];
  unsigned short* xr = x + (size_t)s * HDIM + threadIdx.x * 8;
  uint4 v = {0u, 0u, 0u, 0u};
  if (t >= 0) {
    const float* tr = tokens + (size_t)t * HDIM + threadIdx.x * 8;
    float4 a = *(const float4*)tr;
    float4 b = *(const float4*)(tr + 4);
    v.x = (unsigned)f2bf(a.x) | ((unsigned)f2bf(a.y) << 16);
    v.y = (unsigned)f2bf(a.z) | ((unsigned)f2bf(a.w) << 16);
    v.z = (unsigned)f2bf(b.x) | ((unsigned)f2bf(b.y) << 16);
    v.w = (unsigned)f2bf(b.z) | ((unsigned)f2bf(b.w) << 16);
  }
  *(uint4*)xr = v;
}

// ================= 4-phase/tile 256xBN BK=64 mainloop (r13 + kk-outer mmq) ===========
// Best-measured configuration (746 us total). Quadrant order (0,0),(1,0),(1,1),(0,1);
// held frag sets aA=A0,aB=A1,bA=B0,bB=B1; P1 reads aA,bA,aB (one exposed lgkm drain
// per tile); P2 prefetches bB under its MFMA; P3/P4 held regs only. Stages:
// P1:B0(t+1) P2:A1(t+1) P3:A0(t+2) P4:B1(t+2); single vmcnt(4) at P4-end.
template<int BN>   // 256 (both gemms)
__device__ __forceinline__ void mainloop8(const unsigned short* __restrict__ Ag,
                                          const unsigned short* __restrict__ Bg,
                                          int lda, int ldb, int nkt,
                                          unsigned short* lds, f32x4 (&acc)[4][BN / 32]) {
  constexpr int NF   = BN / 64;          // n-frags per wave per quadrant
  constexpr int AELB = 256 * 64 * 2;     // A tile bytes per parity (32768)
  constexpr int BELB = BN * 64 * 2;
  constexpr int BHB  = (BN / 2) * 128;   // bytes per B half (row stride 128B)
  int tid = threadIdx.x, lane = tid & 63, wid = tid >> 6;
  int qr = wid >> 1, qc = wid & 1;
  int fr = lane & 15, fg = lane >> 4;

  char* ldsc = (char*)lds;
  int swz0 = ((fg       ^ (fr & 7)) << 4);
  int swz1 = (((4 | fg) ^ (fr & 7)) << 4);
  const char* a_b0 = ldsc + (qr * 32 + fr) * 128 + swz0;
  const char* a_b1 = ldsc + (qr * 32 + fr) * 128 + swz1;
  const char* b_b0 = ldsc + 2 * AELB + (qc * (NF * 16) + fr) * 128 + swz0;
  const char* b_b1 = ldsc + 2 * AELB + (qc * (NF * 16) + fr) * 128 + swz1;

  int srow = tid >> 3;
  int sl8  = ((tid & 7) ^ (srow & 7)) * 8;   // pre-swizzled global column offset (ushorts)

  auto stA = [&](int mh, int kt, int pb) {
    char* dst = ldsc + pb + mh * 16384;
    gload_lds16(Ag + (size_t)(mh * 128 + srow) * lda + kt + sl8, dst + tid * 16);
    gload_lds16(Ag + (size_t)(mh * 128 + 64 + srow) * lda + kt + sl8, dst + tid * 16 + 8192);
  };
  auto stB = [&](int nh, int kt, int qb) {
    char* dst = ldsc + 2 * AELB + qb + nh * BHB;
    gload_lds16(Bg + (size_t)(nh * (BN / 2) + srow) * ldb + kt + sl8, dst + tid * 16);
    if constexpr (BN == 256)
      gload_lds16(Bg + (size_t)(nh * (BN / 2) + 64 + srow) * ldb + kt + sl8,
                  dst + tid * 16 + 8192);
  };

  bf16x8 aA[2][2], aB[2][2], bA[NF][2], bB[NF][2];
  auto rdA = [&](bf16x8 (&dst)[2][2], int mh, int pb) {
#pragma unroll
    for (int mf = 0; mf < 2; ++mf) {
      dst[mf][0] = *(const bf16x8*)(a_b0 + pb + mh * 16384 + mf * 2048);
      dst[mf][1] = *(const bf16x8*)(a_b1 + pb + mh * 16384 + mf * 2048);
    }
  };
  auto rdB = [&](bf16x8 (&dst)[NF][2], int nh, int qb) {
#pragma unroll
    for (int nf = 0; nf < NF; ++nf) {
      dst[nf][0] = *(const bf16x8*)(b_b0 + qb + nh * BHB + nf * 2048);
      dst[nf][1] = *(const bf16x8*)(b_b1 + qb + nh * BHB + nf * 2048);
    }
  };
  auto mmq = [&](bf16x8 (&A)[2][2], bf16x8 (&B)[NF][2], int mh, int nh) {
    __builtin_amdgcn_s_setprio(1);
#pragma unroll
    for (int kk = 0; kk < 2; ++kk)        // kk outermost: consecutive MFMAs independent
#pragma unroll
      for (int mf = 0; mf < 2; ++mf)
#pragma unroll
        for (int nf = 0; nf < NF; ++nf)
          acc[mh * 2 + mf][nh * NF + nf] =
              MFMA_BF16(A[mf][kk], B[nf][kk], acc[mh * 2 + mf][nh * NF + nf], 0, 0, 0);
    __builtin_amdgcn_s_setprio(0);
  };

  // prologue: tile0 {A0,B0,A1,B1}, then A0(1), B1(1); retire tile0
  int ktp = (nkt > 1 ? 64 : 0);
  stA(0, 0, 0); stB(0, 0, 0); stA(1, 0, 0); stB(1, 0, 0);
  stA(0, ktp, AELB); stB(1, ktp, BELB);
  if constexpr (BN == 256) VMCNT4(); else VMCNT3();
  BAR();

  for (int t = 0; t < nkt; ++t) {
    int p0 = (t & 1) ? AELB : 0, p1 = AELB - p0;
    int q0 = (t & 1) ? BELB : 0, q1 = BELB - q0;
    int kt1 = ((t + 1 < nkt) ? t + 1 : nkt - 1) * 64;
    int kt2 = ((t + 2 < nkt) ? t + 2 : nkt - 1) * 64;

    // P1: Q(0,0)=aA*bA; rd aA,bA (consumed now) + aB (P2/P3); stage B0(t+1)
    rdA(aA, 0, p0); rdB(bA, 0, q0); rdA(aB, 1, p0);
    stB(0, kt1, q1);
    SCHED0();
    LGKM0();                      // the one exposed drain per tile
    mmq(aA, bA, 0, 0);
    BAR();

    // P2: Q(1,0)=aB*bA; prefetch bB under MFMA; stage A1(t+1)
    rdB(bB, 1, q0);
    stA(1, kt1, p1);
    SCHED0();
    mmq(aB, bA, 1, 0);
    LGKM0();                      // drain bB (hidden under the 16 MFMA above)
    BAR();

    // P3: Q(1,1) — held regs only; stage A0(t+2)
    stA(0, kt2, p0);
    mmq(aB, bB, 1, 1);
    BAR();

    // P4: Q(0,1) — held regs only; stage B1(t+2); single counted vmcnt
    stB(1, kt2, q0);
    mmq(aA, bB, 0, 1);
    if constexpr (BN == 256) VMCNT4(); else VMCNT3();  // retires through A1(t+1)
    BAR();
  }
}

// ---------------- GEMM1: h = silu(x@Wg) * (x@Wu), interleaved wgu B; 256x256
__global__ __launch_bounds__(512, 1)
void gemm1_kernel(const unsigned short* __restrict__ x, const unsigned short* __restrict__ wgu,
                  unsigned short* __restrict__ h) {
  __shared__ unsigned short lds[2 * 256 * 64 + 2 * 256 * 64];
  int flat = blockIdx.x;                 // 2560 blocks
  int e = flat & 7, idx = flat >> 3;     // expert per XCD
  int c = idx >> 4, i = idx & 15;        // chunks of 16 blocks (8bx x 2by)
  int cbx = c / 5, cby = c % 5;
  int bx = cbx * 8 + (i & 7), by = cby * 2 + (i >> 3);
  const unsigned short* Ag = x   + ((size_t)e * CAP + (size_t)by * 256) * HDIM;
  const unsigned short* Bg = wgu + ((size_t)e * 2 * FDIM + (size_t)bx * 256) * HDIM;
  f32x4 acc[4][8];
#pragma unroll
  for (int m = 0; m < 4; ++m)
#pragma unroll
    for (int n = 0; n < 8; ++n) acc[m][n] = (f32x4){0.f, 0.f, 0.f, 0.f};
  mainloop8<256>(Ag, Bg, HDIM, HDIM, HDIM / 64, lds, acc);

  int lane = threadIdx.x & 63, wid = threadIdx.x >> 6;
  int qr = wid >> 1, qc = wid & 1, fr = lane & 15, fg = lane >> 4;
  size_t rbase = (size_t)e * CAP + by * 256;
#pragma unroll
  for (int mi = 0; mi < 4; ++mi) {
    int row0 = (mi >> 1) * 128 + qr * 32 + (mi & 1) * 16 + fg * 4;
#pragma unroll
    for (int nh = 0; nh < 2; ++nh)
#pragma unroll
      for (int nf = 0; nf < 2; ++nf) {
        int fcol = bx * 128 + (nh * 2 + qc) * 32 + nf * 16 + fr;
#pragma unroll
        for (int v = 0; v < 4; ++v) {
          float g = acc[mi][nh * 4 + nf][v];
          float u = acc[mi][nh * 4 + nf + 2][v];
          float s = g / (1.f + __expf(-g));
          h[(rbase + row0 + v) * FDIM + fcol] = f2bf(s * u);
        }
      }
  }
}

// ---------------- GEMM2: y_ks = h[:,ks*2048:+2048] @ Wd[ks-half]; 256x256, bf16 out
__global__ __launch_bounds__(512, 1)
void gemm2_kernel(const unsigned short* __restrict__ h, const unsigned short* __restrict__ wdT,
                  unsigned short* __restrict__ y0, unsigned short* __restrict__ y1) {
  __shared__ unsigned short lds[2 * 256 * 64 + 2 * 256 * 64];
  int flat = blockIdx.x;                 // 640 blocks
  int e = flat & 7, idx = flat >> 3;     // [0,80)
  int ks = idx & 1, r2 = idx >> 1;       // [0,40)
  int bx = r2 & 3, by = r2 >> 2;         // 4 bx x 10 by
  int k0 = ks * 2048;
  const unsigned short* Ag = h   + ((size_t)e * CAP  + (size_t)by * 256) * FDIM + k0;
  const unsigned short* Bg = wdT + ((size_t)e * HDIM + (size_t)bx * 256) * FDIM + k0;
  f32x4 acc[4][8];
#pragma unroll
  for (int m = 0; m < 4; ++m)
#pragma unroll
    for (int n = 0; n < 8; ++n) acc[m][n] = (f32x4){0.f, 0.f, 0.f, 0.f};
  mainloop8<256>(Ag, Bg, FDIM, FDIM, 2048 / 64, lds, acc);

  unsigned short* yk = ks ? y1 : y0;
  int lane = threadIdx.x & 63, wid = threadIdx.x >> 6;
  int qr = wid >> 1, qc = wid & 1, fr = lane & 15, fg = lane >> 4;
  size_t rbase = (size_t)e * CAP + by * 256;
#pragma unroll
  for (int mi = 0; mi < 4; ++mi) {
    int row0 = (mi >> 1) * 128 + qr * 32 + (mi & 1) * 16 + fg * 4;
#pragma unroll
    for (int nh = 0; nh < 2; ++nh)
#pragma unroll
      for (int nf = 0; nf < 4; ++nf) {
        int col = bx * 256 + nh * 128 + qc * 64 + nf * 16 + fr;
#pragma unroll
        for (int v = 0; v < 4; ++v)
          yk[(rbase + row0 + v) * HDIM + col] = f2bf(acc[mi][nh * 4 + nf][v]);
      }
  }
}

// ---------------- combine: out[t] = sum_k w_k * (y0[e_k,slot_k] + y1[e_k,slot_k])
__global__ __launch_bounds__(256)
void combine_kernel(const unsigned short* __restrict__ y0, const unsigned short* __restrict__ y1,
                    const int* __restrict__ topsel, const int* __restrict__ slot,
                    const float* __restrict__ wts, float* __restrict__ out) {
  int t = blockIdx.x;
  int i = threadIdx.x * 4;
  float4 s = {0.f, 0.f, 0.f, 0.f};
#pragma unroll
  for (int k = 0; k < 2; ++k) {
    int sl = slot[t * 2 + k];
    if (sl >= 0) {
      int e = topsel[t * 2 + k];
      float w = wts[t * 2 + k];
      size_t base = ((size_t)e * CAP + sl) * HDIM + i;
      uint2 a = *(const uint2*)(y0 + base);
      uint2 b = *(const uint2*)(y1 + base);
      s.x += w * (bf2f((unsigned short)(a.x & 0xFFFF)) + bf2f((unsigned short)(b.x & 0xFFFF)));
      s.y += w * (bf2f((unsigned short)(a.x >> 16))    + bf2f((unsigned short)(b.x >> 16)));
      s.z += w * (bf2f((unsigned short)(a.y & 0xFFFF)) + bf2f((unsigned short)(b.y & 0xFFFF)));
      s.w += w * (bf2f((unsigned short)(a.y >> 16))    + bf2f((unsigned short)(b.y >> 16)));
    }
  }
  *(float4*)(out + (size_t)t * HDIM + i) = s;
}

extern "C" void kernel_launch(void* const* d_in, const int* in_sizes, int n_in,
                              void* d_out, int out_size, void* d_ws, size_t ws_size,
                              hipStream_t stream) {
  const float* tokens   = (const float*)d_in[0];
  const float* w_router = (const float*)d_in[1];
  const float* w_gate   = (const float*)d_in[2];
  const float* w_up     = (const float*)d_in[3];
  const float* w_down   = (const float*)d_in[4];
  float* out = (float*)d_out;
  char* ws = (char*)d_ws;

  const size_t WGU = (size_t)NE * 2 * FDIM * HDIM * 2;  // 128 MiB interleaved gate/up bf16
  const size_t WD  = (size_t)NE * HDIM * FDIM * 2;      // 64 MiB
  const size_t XB  = (size_t)NE * CAP * HDIM * 2;       // 40 MiB
  const size_t HB  = (size_t)NE * CAP * FDIM * 2;       // 160 MiB
  const size_t YB  = (size_t)NE * CAP * HDIM * 2;       // 40 MiB (bf16 y per split)
  unsigned short* wguT = (unsigned short*)(ws);
  unsigned short* wdT  = (unsigned short*)(ws + WGU);
  unsigned short* xbuf = (unsigned short*)(ws + WGU + WD);
  unsigned short* hbuf = (unsigned short*)(ws + WGU + WD + XB);
  unsigned short* ybuf0 = (unsigned short*)(ws);        // aliases wguT (dead after gemm1)
  unsigned short* ybuf1 = (unsigned short*)(ws + YB);   // still within WGU's 128 MiB
  char* tail = ws + WGU + WD + XB + HB;
  int*   topsel  = (int*)tail;
  float* wtsv    = (float*)(tail + (size_t)T_TOK * 2 * 4);
  int*   slotv   = (int*)(tail + (size_t)T_TOK * 2 * 8);
  int*   src_tok = (int*)(tail + (size_t)T_TOK * 2 * 12);

  hipMemsetAsync(src_tok, 0xFF, (size_t)NE * CAP * 4, stream);

  transpose_cvt_gu<<<dim3(FDIM / 64, HDIM / 64, NE), 256, 0, stream>>>(w_gate, wguT, 0);
  transpose_cvt_gu<<<dim3(FDIM / 64, HDIM / 64, NE), 256, 0, stream>>>(w_up,   wguT, 1);
  transpose_cvt<<<dim3(HDIM / 64, FDIM / 64, NE), 256, 0, stream>>>(w_down, wdT, FDIM, HDIM);

  router_kernel<<<T_TOK / 4, 256, 0, stream>>>(tokens, w_router, topsel, wtsv);
  dispatch_kernel<<<NE, 256, 0, stream>>>(topsel, slotv, src_tok);
  gather_x<<<NE * CAP, 128, 0, stream>>>(tokens, src_tok, xbuf);

  gemm1_kernel<<<2560, 512, 0, stream>>>(xbuf, wguT, hbuf);
  gemm2_kernel<<<640, 512, 0, stream>>>(hbuf, wdT, ybuf0, ybuf1);

  combine_kernel<<<T_TOK, 256, 0, stream>>>(ybuf0, ybuf1, topsel, slotv, wtsv, out);
}

// Round 18
// 740.894 us; speedup vs baseline: 1.4956x; 1.0075x over previous
//
#include <hip/hip_runtime.h>
#include <hip/hip_bf16.h>
#include <stdint.h>

#define T_TOK 16384
#define HDIM  1024
#define FDIM  4096
#define NE    8
#define CAP   2560   // ceil(1.25 * 16384 / 8)

typedef __attribute__((ext_vector_type(8))) __bf16 bf16x8;
typedef __attribute__((ext_vector_type(4))) float  f32x4;

#define MFMA_BF16 __builtin_amdgcn_mfma_f32_16x16x32_bf16
#define VMCNT3()  asm volatile("s_waitcnt vmcnt(3)" ::: "memory")
#define VMCNT4()  asm volatile("s_waitcnt vmcnt(4)" ::: "memory")
#define LGKM0()   asm volatile("s_waitcnt lgkmcnt(0)" ::: "memory")
#define BAR()     __builtin_amdgcn_s_barrier()
#define SCHED0()  __builtin_amdgcn_sched_barrier(0)

__device__ __forceinline__ unsigned short f2bf(float f) {
  union { float f; unsigned u; } c; c.f = f;
  unsigned u = c.u;
  return (unsigned short)((u + 0x7FFFu + ((u >> 16) & 1u)) >> 16);
}

__device__ __forceinline__ float bf2f(unsigned short u) {
  union { unsigned u; float f; } c; c.u = ((unsigned)u) << 16;
  return c.f;
}

__device__ __forceinline__ void gload_lds16(const void* g, void* lds) {
  __builtin_amdgcn_global_load_lds((const __attribute__((address_space(1))) void*)g,
                                   (__attribute__((address_space(3))) void*)lds,
                                   16, 0, 0);
}

// ---------------- fused weight transposes (one launch, 24576 blocks):
//   flat <  8192 : w_gate -> wguT (interleaved rows, up=0)
//   flat < 16384 : w_up   -> wguT (interleaved rows, up=1)
//   else         : w_down -> wdT  (plain (E,F,H) -> (E,H,F))
__global__ __launch_bounds__(256)
void transpose_all(const float* __restrict__ w_gate, const float* __restrict__ w_up,
                   const float* __restrict__ w_down,
                   unsigned short* __restrict__ wguT, unsigned short* __restrict__ wdT) {
  __shared__ unsigned short tile[64][68];
  int flat = blockIdx.x;
  if (flat < 16384) {
    // gate/up -> interleaved wgu: rows (grp*64 + 0..31)=gate, (+32..63)=up
    int up = (flat >= 8192) ? 1 : 0;
    int r  = flat & 8191;
    int bx = r & 63, by = (r >> 6) & 15, e = r >> 10;
    int rb = by << 6, cb = bx << 6;      // rb over HDIM rows, cb over FDIM cols
    const float* inp = (up ? w_up : w_gate) + (size_t)e * HDIM * FDIM;
    unsigned short* op = wguT + (size_t)e * 2 * FDIM * HDIM;
    int lc  = threadIdx.x & 63;
    int lr0 = threadIdx.x >> 6;
#pragma unroll
    for (int rr = 0; rr < 64; rr += 4) {
      int rw = rr + lr0;
      float v = inp[(size_t)(rb + rw) * FDIM + cb + lc];
      tile[lc][rw] = f2bf(v);
    }
    __syncthreads();
    int c0 = threadIdx.x >> 3;
    int h0 = (threadIdx.x & 7) << 3;
#pragma unroll
    for (int cc = 0; cc < 64; cc += 32) {
      int c = cc + c0;
      int C = cb + c;
      int orow = ((C >> 5) << 6) + (C & 31) + (up << 5);
      uint2 v0 = *(const uint2*)&tile[c][h0];
      uint2 v1 = *(const uint2*)&tile[c][h0 + 4];
      uint4 v; v.x = v0.x; v.y = v0.y; v.z = v1.x; v.w = v1.y;
      *(uint4*)(op + (size_t)orow * HDIM + rb + h0) = v;
    }
  } else {
    // w_down (E, FDIM, HDIM) f32 -> wdT (E, HDIM, FDIM) bf16
    int r  = flat - 16384;
    int bx = r & 15, by = (r >> 4) & 63, e = r >> 10;
    int rb = by << 6, cb = bx << 6;      // rb over FDIM rows, cb over HDIM cols
    const float* inp = w_down + (size_t)e * FDIM * HDIM;
    unsigned short* op = wdT + (size_t)e * FDIM * HDIM;
    int lc  = threadIdx.x & 63;
    int lr0 = threadIdx.x >> 6;
#pragma unroll
    for (int rr = 0; rr < 64; rr += 4) {
      int rw = rr + lr0;
      float v = inp[(size_t)(rb + rw) * HDIM + cb + lc];
      tile[lc][rw] = f2bf(v);
    }
    __syncthreads();
    int c0 = threadIdx.x >> 3;
    int h0 = (threadIdx.x & 7) << 3;
#pragma unroll
    for (int cc = 0; cc < 64; cc += 32) {
      int c = cc + c0;
      uint2 v0 = *(const uint2*)&tile[c][h0];
      uint2 v1 = *(const uint2*)&tile[c][h0 + 4];
      uint4 v; v.x = v0.x; v.y = v0.y; v.z = v1.x; v.w = v1.y;
      *(uint4*)(op + (size_t)(cb + c) * FDIM + rb + h0) = v;
    }
  }
}

// ---------------- router: 1 wave per token, fp32 logits, top-2
__global__ __launch_bounds__(256)
void router_kernel(const float* __restrict__ tokens, const float* __restrict__ wr,
                   int* __restrict__ topsel, float* __restrict__ wts) {
  int lane = threadIdx.x & 63;
  int t = (blockIdx.x << 2) + (threadIdx.x >> 6);
  const float* tok = tokens + (size_t)t * HDIM;
  float acc[8];
#pragma unroll
  for (int i = 0; i < 8; ++i) acc[i] = 0.f;
#pragma unroll
  for (int j = 0; j < 4; ++j) {
    int h0 = j * 256 + lane * 4;
    float4 tv = *(const float4*)(tok + h0);
    const float* w = wr + (size_t)h0 * 8;
#pragma unroll
    for (int q = 0; q < 4; ++q) {
      float xv = ((const float*)&tv)[q];
      float4 wa = *(const float4*)(w + q * 8);
      float4 wb = *(const float4*)(w + q * 8 + 4);
      acc[0] += xv * wa.x; acc[1] += xv * wa.y; acc[2] += xv * wa.z; acc[3] += xv * wa.w;
      acc[4] += xv * wb.x; acc[5] += xv * wb.y; acc[6] += xv * wb.z; acc[7] += xv * wb.w;
    }
  }
#pragma unroll
  for (int off = 1; off < 64; off <<= 1) {
#pragma unroll
    for (int i = 0; i < 8; ++i) acc[i] += __shfl_xor(acc[i], off, 64);
  }
  if (lane == 0) {
    int e0 = 0; float v0 = acc[0];
#pragma unroll
    for (int i = 1; i < 8; ++i) if (acc[i] > v0) { v0 = acc[i]; e0 = i; }
    int e1 = -1; float v1 = -3.4e38f;
#pragma unroll
    for (int i = 0; i < 8; ++i) if (i != e0 && acc[i] > v1) { v1 = acc[i]; e1 = i; }
    float w0 = 1.f / (1.f + __expf(v1 - v0));
    topsel[t * 2] = e0; topsel[t * 2 + 1] = e1;
    wts[t * 2] = w0;    wts[t * 2 + 1] = 1.f - w0;
  }
}

// ---------------- dispatch: per-expert block; 3-pass (count / scan / assign)
__global__ __launch_bounds__(256)
void dispatch_kernel(const int* __restrict__ topsel, int* __restrict__ slot,
                     int* __restrict__ src_tok) {
  int e = blockIdx.x;           // 8 blocks
  int w = threadIdx.x >> 6, lane = threadIdx.x & 63;
  __shared__ int gcnt[2][256];
  __shared__ int tot[2];
#pragma unroll
  for (int k = 0; k < 2; ++k)
    for (int g = w; g < 256; g += 4) {
      int ch = topsel[(g * 64 + lane) * 2 + k];
      unsigned long long m = __ballot(ch == e);
      if (lane == 0) gcnt[k][g] = __popcll(m);
    }
  __syncthreads();
  if (w < 2) {
    int k = w;
    int c0 = gcnt[k][lane * 4], c1 = gcnt[k][lane * 4 + 1];
    int c2 = gcnt[k][lane * 4 + 2], c3 = gcnt[k][lane * 4 + 3];
    int s = c0 + c1 + c2 + c3;
    int inc = s;
#pragma unroll
    for (int off = 1; off < 64; off <<= 1) {
      int v = __shfl_up(inc, off, 64);
      if (lane >= off) inc += v;
    }
    int base = inc - s;
    gcnt[k][lane * 4] = base;
    gcnt[k][lane * 4 + 1] = base + c0;
    gcnt[k][lane * 4 + 2] = base + c0 + c1;
    gcnt[k][lane * 4 + 3] = base + c0 + c1 + c2;
    if (lane == 63) tot[k] = inc;
  }
  __syncthreads();
#pragma unroll
  for (int k = 0; k < 2; ++k) {
    int kbase = (k == 1) ? tot[0] : 0;
    for (int g = w; g < 256; g += 4) {
      int t = g * 64 + lane;
      int ch = topsel[t * 2 + k];
      unsigned long long m = __ballot(ch == e);
      if (ch == e) {
        unsigned long long lmask = lane ? (~0ull >> (64 - lane)) : 0ull;
        int r = kbase + gcnt[k][g] + __popcll(m & lmask);
        if (r < CAP) { slot[t * 2 + k] = r; src_tok[e * CAP + r] = t; }
        else         { slot[t * 2 + k] = -1; }
      }
    }
  }
}

// ---------------- gather tokens -> bf16 x (E*CAP, HDIM); zero unfilled slots
__global__ __launch_bounds__(128)
void gather_x(const float* __restrict__ tokens, const int* __restrict__ src_tok,
              unsigned short* __restrict__ x) {
  int s = blockIdx.x;
  int t = src_tok[s];
  unsigned short* xr = x + (size_t)s * HDIM + threadIdx.x * 8;
  uint4 v = {0u, 0u, 0u, 0u};
  if (t >= 0) {
    const float* tr = tokens + (size_t)t * HDIM + threadIdx.x * 8;
    float4 a = *(const float4*)tr;
    float4 b = *(const float4*)(tr + 4);
    v.x = (unsigned)f2bf(a.x) | ((unsigned)f2bf(a.y) << 16);
    v.y = (unsigned)f2bf(a.z) | ((unsigned)f2bf(a.w) << 16);
    v.z = (unsigned)f2bf(b.x) | ((unsigned)f2bf(b.y) << 16);
    v.w = (unsigned)f2bf(b.z) | ((unsigned)f2bf(b.w) << 16);
  }
  *(uint4*)xr = v;
}

// ================= 4-phase/tile 256xBN BK=64 mainloop (best-measured, r15) ===========
// Quadrant order (0,0),(1,0),(1,1),(0,1); held frag sets aA=A0,aB=A1,bA=B0,bB=B1;
// P1 reads aA,bA,aB (one exposed lgkm drain per tile); P2 prefetches bB under its
// MFMA; P3/P4 held regs only. Stages: P1:B0(t+1) P2:A1(t+1) P3:A0(t+2) P4:B1(t+2);
// single vmcnt(4) at P4-end. kk-outer mmq (independent consecutive MFMAs).
template<int BN>   // 256 (both gemms)
__device__ __forceinline__ void mainloop8(const unsigned short* __restrict__ Ag,
                                          const unsigned short* __restrict__ Bg,
                                          int lda, int ldb, int nkt,
                                          unsigned short* lds, f32x4 (&acc)[4][BN / 32]) {
  constexpr int NF   = BN / 64;          // n-frags per wave per quadrant
  constexpr int AELB = 256 * 64 * 2;     // A tile bytes per parity (32768)
  constexpr int BELB = BN * 64 * 2;
  constexpr int BHB  = (BN / 2) * 128;   // bytes per B half (row stride 128B)
  int tid = threadIdx.x, lane = tid & 63, wid = tid >> 6;
  int qr = wid >> 1, qc = wid & 1;
  int fr = lane & 15, fg = lane >> 4;

  char* ldsc = (char*)lds;
  int swz0 = ((fg       ^ (fr & 7)) << 4);
  int swz1 = (((4 | fg) ^ (fr & 7)) << 4);
  const char* a_b0 = ldsc + (qr * 32 + fr) * 128 + swz0;
  const char* a_b1 = ldsc + (qr * 32 + fr) * 128 + swz1;
  const char* b_b0 = ldsc + 2 * AELB + (qc * (NF * 16) + fr) * 128 + swz0;
  const char* b_b1 = ldsc + 2 * AELB + (qc * (NF * 16) + fr) * 128 + swz1;

  int srow = tid >> 3;
  int sl8  = ((tid & 7) ^ (srow & 7)) * 8;   // pre-swizzled global column offset (ushorts)

  auto stA = [&](int mh, int kt, int pb) {
    char* dst = ldsc + pb + mh * 16384;
    gload_lds16(Ag + (size_t)(mh * 128 + srow) * lda + kt + sl8, dst + tid * 16);
    gload_lds16(Ag + (size_t)(mh * 128 + 64 + srow) * lda + kt + sl8, dst + tid * 16 + 8192);
  };
  auto stB = [&](int nh, int kt, int qb) {
    char* dst = ldsc + 2 * AELB + qb + nh * BHB;
    gload_lds16(Bg + (size_t)(nh * (BN / 2) + srow) * ldb + kt + sl8, dst + tid * 16);
    if constexpr (BN == 256)
      gload_lds16(Bg + (size_t)(nh * (BN / 2) + 64 + srow) * ldb + kt + sl8,
                  dst + tid * 16 + 8192);
  };

  bf16x8 aA[2][2], aB[2][2], bA[NF][2], bB[NF][2];
  auto rdA = [&](bf16x8 (&dst)[2][2], int mh, int pb) {
#pragma unroll
    for (int mf = 0; mf < 2; ++mf) {
      dst[mf][0] = *(const bf16x8*)(a_b0 + pb + mh * 16384 + mf * 2048);
      dst[mf][1] = *(const bf16x8*)(a_b1 + pb + mh * 16384 + mf * 2048);
    }
  };
  auto rdB = [&](bf16x8 (&dst)[NF][2], int nh, int qb) {
#pragma unroll
    for (int nf = 0; nf < NF; ++nf) {
      dst[nf][0] = *(const bf16x8*)(b_b0 + qb + nh * BHB + nf * 2048);
      dst[nf][1] = *(const bf16x8*)(b_b1 + qb + nh * BHB + nf * 2048);
    }
  };
  auto mmq = [&](bf16x8 (&A)[2][2], bf16x8 (&B)[NF][2], int mh, int nh) {
    __builtin_amdgcn_s_setprio(1);
#pragma unroll
    for (int kk = 0; kk < 2; ++kk)        // kk outermost: consecutive MFMAs independent
#pragma unroll
      for (int mf = 0; mf < 2; ++mf)
#pragma unroll
        for (int nf = 0; nf < NF; ++nf)
          acc[mh * 2 + mf][nh * NF + nf] =
              MFMA_BF16(A[mf][kk], B[nf][kk], acc[mh * 2 + mf][nh * NF + nf], 0, 0, 0);
    __builtin_amdgcn_s_setprio(0);
  };

  // prologue: tile0 {A0,B0,A1,B1}, then A0(1), B1(1); retire tile0
  int ktp = (nkt > 1 ? 64 : 0);
  stA(0, 0, 0); stB(0, 0, 0); stA(1, 0, 0); stB(1, 0, 0);
  stA(0, ktp, AELB); stB(1, ktp, BELB);
  if constexpr (BN == 256) VMCNT4(); else VMCNT3();
  BAR();

  for (int t = 0; t < nkt; ++t) {
    int p0 = (t & 1) ? AELB : 0, p1 = AELB - p0;
    int q0 = (t & 1) ? BELB : 0, q1 = BELB - q0;
    int kt1 = ((t + 1 < nkt) ? t + 1 : nkt - 1) * 64;
    int kt2 = ((t + 2 < nkt) ? t + 2 : nkt - 1) * 64;

    // P1: Q(0,0)=aA*bA; rd aA,bA (consumed now) + aB (P2/P3); stage B0(t+1)
    rdA(aA, 0, p0); rdB(bA, 0, q0); rdA(aB, 1, p0);
    stB(0, kt1, q1);
    SCHED0();
    LGKM0();                      // the one exposed drain per tile
    mmq(aA, bA, 0, 0);
    BAR();

    // P2: Q(1,0)=aB*bA; prefetch bB under MFMA; stage A1(t+1)
    rdB(bB, 1, q0);
    stA(1, kt1, p1);
    SCHED0();
    mmq(aB, bA, 1, 0);
    LGKM0();                      // drain bB (hidden under the 16 MFMA above)
    BAR();

    // P3: Q(1,1) — held regs only; stage A0(t+2)
    stA(0, kt2, p0);
    mmq(aB, bB, 1, 1);
    BAR();

    // P4: Q(0,1) — held regs only; stage B1(t+2); single counted vmcnt
    stB(1, kt2, q0);
    mmq(aA, bB, 0, 1);
    if constexpr (BN == 256) VMCNT4(); else VMCNT3();  // retires through A1(t+1)
    BAR();
  }
}

// ---------------- GEMM1: h = silu(x@Wg) * (x@Wu), interleaved wgu B; 256x256
__global__ __launch_bounds__(512, 1)
void gemm1_kernel(const unsigned short* __restrict__ x, const unsigned short* __restrict__ wgu,
                  unsigned short* __restrict__ h) {
  __shared__ unsigned short lds[2 * 256 * 64 + 2 * 256 * 64];
  int flat = blockIdx.x;                 // 2560 blocks
  int e = flat & 7, idx = flat >> 3;     // expert per XCD
  int c = idx >> 4, i = idx & 15;        // chunks of 16 blocks (8bx x 2by)
  int cbx = c / 5, cby = c % 5;
  int bx = cbx * 8 + (i & 7), by = cby * 2 + (i >> 3);
  const unsigned short* Ag = x   + ((size_t)e * CAP + (size_t)by * 256) * HDIM;
  const unsigned short* Bg = wgu + ((size_t)e * 2 * FDIM + (size_t)bx * 256) * HDIM;
  f32x4 acc[4][8];
#pragma unroll
  for (int m = 0; m < 4; ++m)
#pragma unroll
    for (int n = 0; n < 8; ++n) acc[m][n] = (f32x4){0.f, 0.f, 0.f, 0.f};
  mainloop8<256>(Ag, Bg, HDIM, HDIM, HDIM / 64, lds, acc);

  int lane = threadIdx.x & 63, wid = threadIdx.x >> 6;
  int qr = wid >> 1, qc = wid & 1, fr = lane & 15, fg = lane >> 4;
  size_t rbase = (size_t)e * CAP + by * 256;
#pragma unroll
  for (int mi = 0; mi < 4; ++mi) {
    int row0 = (mi >> 1) * 128 + qr * 32 + (mi & 1) * 16 + fg * 4;
#pragma unroll
    for (int nh = 0; nh < 2; ++nh)
#pragma unroll
      for (int nf = 0; nf < 2; ++nf) {
        int fcol = bx * 128 + (nh * 2 + qc) * 32 + nf * 16 + fr;
#pragma unroll
        for (int v = 0; v < 4; ++v) {
          float g = acc[mi][nh * 4 + nf][v];
          float u = acc[mi][nh * 4 + nf + 2][v];
          float s = g / (1.f + __expf(-g));
          h[(rbase + row0 + v) * FDIM + fcol] = f2bf(s * u);
        }
      }
  }
}

// ---------------- GEMM2: y_ks = h[:,ks*2048:+2048] @ Wd[ks-half]; 256x256, bf16 out
__global__ __launch_bounds__(512, 1)
void gemm2_kernel(const unsigned short* __restrict__ h, const unsigned short* __restrict__ wdT,
                  unsigned short* __restrict__ y0, unsigned short* __restrict__ y1) {
  __shared__ unsigned short lds[2 * 256 * 64 + 2 * 256 * 64];
  int flat = blockIdx.x;                 // 640 blocks
  int e = flat & 7, idx = flat >> 3;     // [0,80)
  int ks = idx & 1, r2 = idx >> 1;       // [0,40)
  int bx = r2 & 3, by = r2 >> 2;         // 4 bx x 10 by
  int k0 = ks * 2048;
  const unsigned short* Ag = h   + ((size_t)e * CAP  + (size_t)by * 256) * FDIM + k0;
  const unsigned short* Bg = wdT + ((size_t)e * HDIM + (size_t)bx * 256) * FDIM + k0;
  f32x4 acc[4][8];
#pragma unroll
  for (int m = 0; m < 4; ++m)
#pragma unroll
    for (int n = 0; n < 8; ++n) acc[m][n] = (f32x4){0.f, 0.f, 0.f, 0.f};
  mainloop8<256>(Ag, Bg, FDIM, FDIM, 2048 / 64, lds, acc);

  unsigned short* yk = ks ? y1 : y0;
  int lane = threadIdx.x & 63, wid = threadIdx.x >> 6;
  int qr = wid >> 1, qc = wid & 1, fr = lane & 15, fg = lane >> 4;
  size_t rbase = (size_t)e * CAP + by * 256;
#pragma unroll
  for (int mi = 0; mi < 4; ++mi) {
    int row0 = (mi >> 1) * 128 + qr * 32 + (mi & 1) * 16 + fg * 4;
#pragma unroll
    for (int nh = 0; nh < 2; ++nh)
#pragma unroll
      for (int nf = 0; nf < 4; ++nf) {
        int col = bx * 256 + nh * 128 + qc * 64 + nf * 16 + fr;
#pragma unroll
        for (int v = 0; v < 4; ++v)
          yk[(rbase + row0 + v) * HDIM + col] = f2bf(acc[mi][nh * 4 + nf][v]);
      }
  }
}

// ---------------- combine: out[t] = sum_k w_k * (y0[e_k,slot_k] + y1[e_k,slot_k])
__global__ __launch_bounds__(256)
void combine_kernel(const unsigned short* __restrict__ y0, const unsigned short* __restrict__ y1,
                    const int* __restrict__ topsel, const int* __restrict__ slot,
                    const float* __restrict__ wts, float* __restrict__ out) {
  int t = blockIdx.x;
  int i = threadIdx.x * 4;
  float4 s = {0.f, 0.f, 0.f, 0.f};
#pragma unroll
  for (int k = 0; k < 2; ++k) {
    int sl = slot[t * 2 + k];
    if (sl >= 0) {
      int e = topsel[t * 2 + k];
      float w = wts[t * 2 + k];
      size_t base = ((size_t)e * CAP + sl) * HDIM + i;
      uint2 a = *(const uint2*)(y0 + base);
      uint2 b = *(const uint2*)(y1 + base);
      s.x += w * (bf2f((unsigned short)(a.x & 0xFFFF)) + bf2f((unsigned short)(b.x & 0xFFFF)));
      s.y += w * (bf2f((unsigned short)(a.x >> 16))    + bf2f((unsigned short)(b.x >> 16)));
      s.z += w * (bf2f((unsigned short)(a.y & 0xFFFF)) + bf2f((unsigned short)(b.y & 0xFFFF)));
      s.w += w * (bf2f((unsigned short)(a.y >> 16))    + bf2f((unsigned short)(b.y >> 16)));
    }
  }
  *(float4*)(out + (size_t)t * HDIM + i) = s;
}

extern "C" void kernel_launch(void* const* d_in, const int* in_sizes, int n_in,
                              void* d_out, int out_size, void* d_ws, size_t ws_size,
                              hipStream_t stream) {
  const float* tokens   = (const float*)d_in[0];
  const float* w_router = (const float*)d_in[1];
  const float* w_gate   = (const float*)d_in[2];
  const float* w_up     = (const float*)d_in[3];
  const float* w_down   = (const float*)d_in[4];
  float* out = (float*)d_out;
  char* ws = (char*)d_ws;

  const size_t WGU = (size_t)NE * 2 * FDIM * HDIM * 2;  // 128 MiB interleaved gate/up bf16
  const size_t WD  = (size_t)NE * HDIM * FDIM * 2;      // 64 MiB
  const size_t XB  = (size_t)NE * CAP * HDIM * 2;       // 40 MiB
  const size_t HB  = (size_t)NE * CAP * FDIM * 2;       // 160 MiB
  const size_t YB  = (size_t)NE * CAP * HDIM * 2;       // 40 MiB (bf16 y per split)
  unsigned short* wguT = (unsigned short*)(ws);
  unsigned short* wdT  = (unsigned short*)(ws + WGU);
  unsigned short* xbuf = (unsigned short*)(ws + WGU + WD);
  unsigned short* hbuf = (unsigned short*)(ws + WGU + WD + XB);
  unsigned short* ybuf0 = (unsigned short*)(ws);        // aliases wguT (dead after gemm1)
  unsigned short* ybuf1 = (unsigned short*)(ws + YB);   // still within WGU's 128 MiB
  char* tail = ws + WGU + WD + XB + HB;
  int*   topsel  = (int*)tail;
  float* wtsv    = (float*)(tail + (size_t)T_TOK * 2 * 4);
  int*   slotv   = (int*)(tail + (size_t)T_TOK * 2 * 8);
  int*   src_tok = (int*)(tail + (size_t)T_TOK * 2 * 12);

  hipMemsetAsync(src_tok, 0xFF, (size_t)NE * CAP * 4, stream);

  transpose_all<<<24576, 256, 0, stream>>>(w_gate, w_up, w_down, wguT, wdT);

  router_kernel<<<T_TOK / 4, 256, 0, stream>>>(tokens, w_router, topsel, wtsv);
  dispatch_kernel<<<NE, 256, 0, stream>>>(topsel, slotv, src_tok);
  gather_x<<<NE * CAP, 128, 0, stream>>>(tokens, src_tok, xbuf);

  gemm1_kernel<<<2560, 512, 0, stream>>>(xbuf, wguT, hbuf);
  gemm2_kernel<<<640, 512, 0, stream>>>(hbuf, wdT, ybuf0, ybuf1);

  combine_kernel<<<T_TOK, 256, 0, stream>>>(ybuf0, ybuf1, topsel, slotv, wtsv, out);
}